// Round 4
// baseline (21219.865 us; speedup 1.0000x reference)
//
#include <hip/hip_runtime.h>

// Seq2Seq GRU + Bahdanau attention, fp32. B=32 S=64 T=48 E=512 H=1024 V=32000.
// R4: persistent recurrence, fence-free monotonic barrier, batched coherent
// register staging (global_load_dwordx4 sc0 sc1 + single vmcnt wait), q-proj
// in GRU blocks (no wq redundancy), nt-loads for streaming operands.

#define BB 32
#define SS 64
#define TT 48
#define TD 47
#define EE 512
#define HH 1024
#define GG 3072
#define VV 32000
#define SOS_IDX 1
#define NBE 128          // encoder blocks
#define NBG 128          // decoder GRU blocks (8 j-cols each)
#define NBA 32           // decoder attention blocks (1 batch each)
#define NBD (NBG + NBA)
#define NTHR 512

typedef float f32x4 __attribute__((ext_vector_type(4)));

static __device__ __forceinline__ float sigmoid_f(float x) {
    return 1.0f / (1.0f + __expf(-x));
}
static __device__ __forceinline__ float tanh_f(float x) {
    return 1.0f - 2.0f / (__expf(2.0f * x) + 1.0f);
}

// Coherent 16B load/store: bypass (stale) L2, hit the L3 coherence point.
static __device__ __forceinline__ f32x4 cload4(const float* p) {
    f32x4 v;
    asm volatile("global_load_dwordx4 %0, %1, off sc0 sc1" : "=v"(v) : "v"(p) : "memory");
    return v;
}
static __device__ __forceinline__ void cstore4(float* p, f32x4 v) {
    asm volatile("global_store_dwordx4 %0, %1, off sc0 sc1" :: "v"(p), "v"(v) : "memory");
}
static __device__ __forceinline__ void cwait() {
    asm volatile("s_waitcnt vmcnt(0)" ::: "memory");
    __builtin_amdgcn_sched_barrier(0);
}
static __device__ __forceinline__ float cload(const float* p) {
    return __hip_atomic_load(p, __ATOMIC_RELAXED, __HIP_MEMORY_SCOPE_AGENT);
}
static __device__ __forceinline__ void cstore(float* p, float v) {
    __hip_atomic_store(p, v, __ATOMIC_RELAXED, __HIP_MEMORY_SCOPE_AGENT);
}

// Monotonic fence-free grid barrier. EVERY wave drains its own vmem stores
// before arrival is published (R3 only drained wave 0's).
static __device__ __forceinline__ void gbar(int* bar, int nblk, int& bstep) {
    asm volatile("s_waitcnt vmcnt(0) lgkmcnt(0)" ::: "memory");
    __syncthreads();
    bstep += 1;
    if (threadIdx.x == 0) {
        int target = bstep * nblk;
        __hip_atomic_fetch_add(bar, 1, __ATOMIC_RELAXED, __HIP_MEMORY_SCOPE_AGENT);
        while (__hip_atomic_load(bar, __ATOMIC_RELAXED, __HIP_MEMORY_SCOPE_AGENT) < target) {
            __builtin_amdgcn_s_sleep(1);
        }
        asm volatile("" ::: "memory");
    }
    __syncthreads();
}

__global__ void k_dec_idx(const int* __restrict__ tgt, int* __restrict__ idx) {
    int m = blockIdx.x * 256 + threadIdx.x;
    if (m < TD * BB) {
        int t = m >> 5, b = m & 31;
        idx[m] = (t == 0) ? SOS_IDX : tgt[b * TT + t];
    }
}

// C[m,n] = sum_k A[row(m),k] * Wt[n,k] + bias[n]
__global__ __launch_bounds__(256) void k_gemm(
    const float* __restrict__ A, const float* __restrict__ Wt,
    const float* __restrict__ bias, float* __restrict__ C,
    const int* __restrict__ rowidx,
    int M, int N, int K, int lda, int ldw, int ldc, int permute)
{
    __shared__ __align__(16) float As[16][64];
    __shared__ __align__(16) float Bs[16][64];
    const int tid = threadIdx.x;
    const int tm = tid >> 4;
    const int tn = tid & 15;
    const int row0 = blockIdx.y * 64;
    const int col0 = blockIdx.x * 64;
    const int lr = tid >> 2;
    const int lq = tid & 3;

    long arow_off = -1;
    {
        int arow = row0 + lr;
        if (arow < M) {
            int r = rowidx ? rowidx[arow] : arow;
            arow_off = (long)r * lda;
        }
    }
    long wrow_off = -1;
    {
        int wcol = col0 + lr;
        if (wcol < N) wrow_off = (long)wcol * ldw;
    }

    float acc[4][4];
#pragma unroll
    for (int i = 0; i < 4; ++i)
#pragma unroll
        for (int j = 0; j < 4; ++j) acc[i][j] = 0.f;

    for (int k0 = 0; k0 < K; k0 += 16) {
        float4 av = make_float4(0.f, 0.f, 0.f, 0.f);
        if (arow_off >= 0) av = *(const float4*)(A + arow_off + k0 + lq * 4);
        float4 wv = make_float4(0.f, 0.f, 0.f, 0.f);
        if (wrow_off >= 0) wv = *(const float4*)(Wt + wrow_off + k0 + lq * 4);
        __syncthreads();
        As[lq * 4 + 0][lr] = av.x; As[lq * 4 + 1][lr] = av.y;
        As[lq * 4 + 2][lr] = av.z; As[lq * 4 + 3][lr] = av.w;
        Bs[lq * 4 + 0][lr] = wv.x; Bs[lq * 4 + 1][lr] = wv.y;
        Bs[lq * 4 + 2][lr] = wv.z; Bs[lq * 4 + 3][lr] = wv.w;
        __syncthreads();
#pragma unroll
        for (int kk = 0; kk < 16; ++kk) {
            float4 a4 = *(const float4*)&As[kk][tm * 4];
            float4 b4 = *(const float4*)&Bs[kk][tn * 4];
            acc[0][0] += a4.x * b4.x; acc[0][1] += a4.x * b4.y;
            acc[0][2] += a4.x * b4.z; acc[0][3] += a4.x * b4.w;
            acc[1][0] += a4.y * b4.x; acc[1][1] += a4.y * b4.y;
            acc[1][2] += a4.y * b4.z; acc[1][3] += a4.y * b4.w;
            acc[2][0] += a4.z * b4.x; acc[2][1] += a4.z * b4.y;
            acc[2][2] += a4.z * b4.z; acc[2][3] += a4.z * b4.w;
            acc[3][0] += a4.w * b4.x; acc[3][1] += a4.w * b4.y;
            acc[3][2] += a4.w * b4.z; acc[3][3] += a4.w * b4.w;
        }
    }

    float4 bv = make_float4(0.f, 0.f, 0.f, 0.f);
    if (bias) bv = *(const float4*)(bias + col0 + tn * 4);
#pragma unroll
    for (int i = 0; i < 4; ++i) {
        int m = row0 + tm * 4 + i;
        if (m >= M) continue;
        int orow = permute ? ((m & 31) * TD + (m >> 5)) : m;
        float4 v;
        v.x = acc[i][0] + bv.x; v.y = acc[i][1] + bv.y;
        v.z = acc[i][2] + bv.z; v.w = acc[i][3] + bv.w;
        *(float4*)(C + (long)orow * ldc + col0 + tn * 4) = v;
    }
}

// hT4 layout: element (k,b) at (k>>2)*128 + b*4 + (k&3).

// ---------------- persistent encoder ----------------
// 128 blocks x 512 thr, 8 j-cols each. Thread = (b=tid&31, ks=tid>>5: k-range 64).
__global__ __launch_bounds__(NTHR, 2) void p_enc(
    const float* __restrict__ gi, const float* __restrict__ Whh,
    const float* __restrict__ bhh, float* hA, float* hB,
    float* __restrict__ enc_out, int* bar)
{
    __shared__ float red[24][16][32];
    const int tid = threadIdx.x, bid = blockIdx.x;
    const int b = tid & 31, ks = tid >> 5;
    const int j0 = bid * 8;
    const int kc = ks * 64;
    int bstep = 0;

    for (int i = bid * NTHR + tid; i < BB * HH; i += NBE * NTHR)
        cstore(hA + i, 0.f);
    gbar(bar, NBE, bstep);

    const float* w0 = Whh + ((size_t)j0 << 10) + kc;
    const float* w1 = Whh + ((size_t)(HH + j0) << 10) + kc;
    const float* w2 = Whh + ((size_t)(2 * HH + j0) << 10) + kc;

    float* cur = hA;
    float* nxt = hB;
    for (int s = 0; s < SS; ++s) {
        // stage h slice into registers (16 coherent 16B loads, one wait)
        f32x4 hreg[16];
        const float* hb = cur + ((kc >> 2) << 7) + (b << 2);
#pragma unroll
        for (int i = 0; i < 16; ++i) hreg[i] = cload4(hb + (i << 7));
        cwait();

        float acc[24];
#pragma unroll
        for (int u = 0; u < 24; ++u) acc[u] = 0.f;
#pragma unroll
        for (int i = 0; i < 16; ++i) {
            f32x4 h4 = hreg[i];
#pragma unroll
            for (int jj = 0; jj < 8; ++jj) {
                f32x4 a4 = *(const f32x4*)(w0 + ((size_t)jj << 10) + (i << 2));
                acc[jj] += h4.x * a4.x + h4.y * a4.y + h4.z * a4.z + h4.w * a4.w;
                f32x4 b4 = *(const f32x4*)(w1 + ((size_t)jj << 10) + (i << 2));
                acc[8 + jj] += h4.x * b4.x + h4.y * b4.y + h4.z * b4.z + h4.w * b4.w;
                f32x4 c4 = *(const f32x4*)(w2 + ((size_t)jj << 10) + (i << 2));
                acc[16 + jj] += h4.x * c4.x + h4.y * c4.y + h4.z * c4.z + h4.w * c4.w;
            }
        }
#pragma unroll
        for (int u = 0; u < 24; ++u) red[u][ks][b] = acc[u];
        __syncthreads();
        if (tid < 256) {
            const int fj = tid >> 5, fb = tid & 31, j = j0 + fj;
            float s0 = 0.f, s1 = 0.f, s2 = 0.f;
#pragma unroll
            for (int q = 0; q < 16; ++q) {
                s0 += red[fj][q][fb];
                s1 += red[8 + fj][q][fb];
                s2 += red[16 + fj][q][fb];
            }
            const float* gr = gi + (size_t)(fb * SS + s) * GG;
            float g0 = __builtin_nontemporal_load(gr + j);
            float g1 = __builtin_nontemporal_load(gr + HH + j);
            float g2 = __builtin_nontemporal_load(gr + 2 * HH + j);
            float r = sigmoid_f(g0 + s0 + bhh[j]);
            float z = sigmoid_f(g1 + s1 + bhh[HH + j]);
            float n = tanh_f(g2 + r * (s2 + bhh[2 * HH + j]));
            float hold = cload(cur + ((j >> 2) << 7) + (fb << 2) + (j & 3));
            float hnew = (1.f - z) * n + z * hold;
            cstore(nxt + ((j >> 2) << 7) + (fb << 2) + (j & 3), hnew);
            enc_out[(size_t)(fb * SS + s) * HH + j] = hnew;
        }
        gbar(bar, NBE, bstep);
        float* tq = cur; cur = nxt; nxt = tq;
    }
}

// ---------------- persistent decoder ----------------
// blocks 0..127: GRU+q (8 j-cols). blocks 128..159: attention (1 batch each).
__global__ __launch_bounds__(NTHR, 2) void p_dec(
    const float* __restrict__ gi, const float* __restrict__ Whh,
    const float* __restrict__ bhh, const float* __restrict__ Wih,
    const float* __restrict__ wq, const float* __restrict__ bq,
    const float* __restrict__ keys, const float* __restrict__ wsv,
    const float* __restrict__ bsv, const int* __restrict__ src,
    const float* __restrict__ enc_out, float* hA, float* hB,
    float* __restrict__ qrow, float* __restrict__ ctxT4,
    float* __restrict__ h2all, float* __restrict__ attn_out, int* bar)
{
    __shared__ float red[24][16][32];     // 48 KB
    __shared__ float shs[3][8][32];
    __shared__ float qs[HH];
    __shared__ float wss[HH];
    __shared__ float sc[8][64];
    __shared__ float wl[64];
    const int tid = threadIdx.x, bid = blockIdx.x;
    const bool isg = bid < NBG;
    int bstep = 0;

    const int b = tid & 31, ks = tid >> 5;
    const int kc = ks * 64;
    const int j0 = bid * 8;
    const int ab = bid - NBG;

    const float* w0 = Whh + ((size_t)j0 << 10) + kc;
    const float* w1 = Whh + ((size_t)(HH + j0) << 10) + kc;
    const float* w2 = Whh + ((size_t)(2 * HH + j0) << 10) + kc;
    const float* wqb = wq + ((size_t)j0 << 10) + kc;
    const float* x0 = Wih + (size_t)(j0) * (EE + HH) + EE + kc;
    const float* x1 = Wih + (size_t)(HH + j0) * (EE + HH) + EE + kc;
    const float* x2 = Wih + (size_t)(2 * HH + j0) * (EE + HH) + EE + kc;

    if (!isg) {
        for (int i = tid; i < HH; i += NTHR) wss[i] = wsv[i];
    }

    float* cur = hA;
    float* nxt = hB;
    for (int t = 0; t < TD; ++t) {
        // ======== P1: GRU blocks: h-side gate dots + q-slice ========
        if (isg) {
            f32x4 hreg[16];
            const float* hb = cur + ((kc >> 2) << 7) + (b << 2);
#pragma unroll
            for (int i = 0; i < 16; ++i) hreg[i] = cload4(hb + (i << 7));
            cwait();

            // pass A: gates r, z
            float acc[16];
#pragma unroll
            for (int u = 0; u < 16; ++u) acc[u] = 0.f;
#pragma unroll
            for (int i = 0; i < 16; ++i) {
                f32x4 h4 = hreg[i];
#pragma unroll
                for (int jj = 0; jj < 8; ++jj) {
                    f32x4 a4 = *(const f32x4*)(w0 + ((size_t)jj << 10) + (i << 2));
                    acc[jj] += h4.x * a4.x + h4.y * a4.y + h4.z * a4.z + h4.w * a4.w;
                    f32x4 b4 = *(const f32x4*)(w1 + ((size_t)jj << 10) + (i << 2));
                    acc[8 + jj] += h4.x * b4.x + h4.y * b4.y + h4.z * b4.z + h4.w * b4.w;
                }
            }
#pragma unroll
            for (int u = 0; u < 16; ++u) red[u][ks][b] = acc[u];
            __syncthreads();
            if (tid < 256) {
                const int fj = tid >> 5, fb = tid & 31;
                float s0 = 0.f, s1 = 0.f;
#pragma unroll
                for (int q = 0; q < 16; ++q) {
                    s0 += red[fj][q][fb];
                    s1 += red[8 + fj][q][fb];
                }
                shs[0][fj][fb] = s0;
                shs[1][fj][fb] = s1;
            }
            __syncthreads();
            // pass B: gate n + q
#pragma unroll
            for (int u = 0; u < 16; ++u) acc[u] = 0.f;
#pragma unroll
            for (int i = 0; i < 16; ++i) {
                f32x4 h4 = hreg[i];
#pragma unroll
                for (int jj = 0; jj < 8; ++jj) {
                    f32x4 a4 = *(const f32x4*)(w2 + ((size_t)jj << 10) + (i << 2));
                    acc[jj] += h4.x * a4.x + h4.y * a4.y + h4.z * a4.z + h4.w * a4.w;
                    f32x4 b4 = *(const f32x4*)(wqb + ((size_t)jj << 10) + (i << 2));
                    acc[8 + jj] += h4.x * b4.x + h4.y * b4.y + h4.z * b4.z + h4.w * b4.w;
                }
            }
#pragma unroll
            for (int u = 0; u < 16; ++u) red[u][ks][b] = acc[u];
            __syncthreads();
            if (tid < 256) {
                const int fj = tid >> 5, fb = tid & 31, j = j0 + fj;
                float sn = 0.f, sq = 0.f;
#pragma unroll
                for (int q = 0; q < 16; ++q) {
                    sn += red[fj][q][fb];
                    sq += red[8 + fj][q][fb];
                }
                shs[2][fj][fb] = sn;
                cstore(qrow + fb * HH + j, sq + bq[j]);
            }
        }
        gbar(bar, NBD, bstep);
        // ======== P2: attention blocks ========
        if (!isg) {
            if (tid < 256) {
                f32x4 qv = cload4(qrow + ab * HH + tid * 4);
                cwait();
                *(f32x4*)&qs[tid * 4] = qv;
            }
            __syncthreads();
            {
                const int s4 = tid >> 3, kq = tid & 7;
                const float* kr = keys + (size_t)(ab * SS + s4) * HH + kq * 128;
                float a = 0.f;
                for (int i = 0; i < 32; ++i) {
                    f32x4 kv = __builtin_nontemporal_load((const f32x4*)(kr + (i << 2)));
                    int k = kq * 128 + (i << 2);
                    a += tanh_f(qs[k] + kv.x) * wss[k]
                       + tanh_f(qs[k + 1] + kv.y) * wss[k + 1]
                       + tanh_f(qs[k + 2] + kv.z) * wss[k + 2]
                       + tanh_f(qs[k + 3] + kv.w) * wss[k + 3];
                }
                sc[kq][s4] = a;
            }
            __syncthreads();
            if (tid < 64) {
                float v = bsv[0];
#pragma unroll
                for (int q = 0; q < 8; ++q) v += sc[q][tid];
                bool valid = src[ab * SS + tid] != 0;
                float m = valid ? v : -3.0e38f;
                for (int off = 32; off; off >>= 1) m = fmaxf(m, __shfl_xor(m, off));
                float e = valid ? __expf(v - m) : 0.f;
                float ssum = e;
                for (int off = 32; off; off >>= 1) ssum += __shfl_xor(ssum, off);
                float wgt = e / ssum;
                wl[tid] = wgt;
                attn_out[((size_t)ab * TD + t) * SS + tid] = wgt;
            }
            __syncthreads();
            if (tid < 256) {
                f32x4 a4 = {0.f, 0.f, 0.f, 0.f};
                const float* er = enc_out + (size_t)ab * SS * HH + tid * 4;
                for (int s2 = 0; s2 < SS; ++s2) {
                    float wgt = wl[s2];
                    f32x4 ev = __builtin_nontemporal_load((const f32x4*)(er + ((size_t)s2 << 10)));
                    a4.x += wgt * ev.x; a4.y += wgt * ev.y;
                    a4.z += wgt * ev.z; a4.w += wgt * ev.w;
                }
                cstore4(ctxT4 + (tid << 7) + (ab << 2), a4);
            }
        }
        gbar(bar, NBD, bstep);
        // ======== P3: GRU blocks: ctx-side dots + finalize ========
        if (isg) {
            f32x4 creg[16];
            const float* cb = ctxT4 + ((kc >> 2) << 7) + (b << 2);
#pragma unroll
            for (int i = 0; i < 16; ++i) creg[i] = cload4(cb + (i << 7));
            cwait();

            float acc[24];
#pragma unroll
            for (int u = 0; u < 24; ++u) acc[u] = 0.f;
#pragma unroll
            for (int i = 0; i < 16; ++i) {
                f32x4 c4 = creg[i];
#pragma unroll
                for (int jj = 0; jj < 8; ++jj) {
                    f32x4 a4 = *(const f32x4*)(x0 + (size_t)jj * (EE + HH) + (i << 2));
                    acc[jj] += c4.x * a4.x + c4.y * a4.y + c4.z * a4.z + c4.w * a4.w;
                    f32x4 b4 = *(const f32x4*)(x1 + (size_t)jj * (EE + HH) + (i << 2));
                    acc[8 + jj] += c4.x * b4.x + c4.y * b4.y + c4.z * b4.z + c4.w * b4.w;
                    f32x4 d4 = *(const f32x4*)(x2 + (size_t)jj * (EE + HH) + (i << 2));
                    acc[16 + jj] += c4.x * d4.x + c4.y * d4.y + c4.z * d4.z + c4.w * d4.w;
                }
            }
#pragma unroll
            for (int u = 0; u < 24; ++u) red[u][ks][b] = acc[u];
            __syncthreads();
            if (tid < 256) {
                const int fj = tid >> 5, fb = tid & 31, j = j0 + fj;
                float sx0 = 0.f, sx1 = 0.f, sx2 = 0.f;
#pragma unroll
                for (int q = 0; q < 16; ++q) {
                    sx0 += red[fj][q][fb];
                    sx1 += red[8 + fj][q][fb];
                    sx2 += red[16 + fj][q][fb];
                }
                const float* gr = gi + (size_t)(t * BB + fb) * GG;
                float g0 = __builtin_nontemporal_load(gr + j);
                float g1 = __builtin_nontemporal_load(gr + HH + j);
                float g2 = __builtin_nontemporal_load(gr + 2 * HH + j);
                float r = sigmoid_f(g0 + sx0 + shs[0][fj][fb] + bhh[j]);
                float z = sigmoid_f(g1 + sx1 + shs[1][fj][fb] + bhh[HH + j]);
                float n = tanh_f(g2 + sx2 + r * (shs[2][fj][fb] + bhh[2 * HH + j]));
                float hold = cload(cur + ((j >> 2) << 7) + (fb << 2) + (j & 3));
                float hnew = (1.f - z) * n + z * hold;
                cstore(nxt + ((j >> 2) << 7) + (fb << 2) + (j & 3), hnew);
                h2all[(size_t)(t * BB + fb) * HH + j] = hnew;
            }
        }
        gbar(bar, NBD, bstep);
        float* tq = cur; cur = nxt; nxt = tq;
    }
}

extern "C" void kernel_launch(void* const* d_in, const int* in_sizes, int n_in,
                              void* d_out, int out_size, void* d_ws, size_t ws_size,
                              hipStream_t stream)
{
    const int*   src  = (const int*)d_in[0];
    const int*   tgt  = (const int*)d_in[1];
    const float* eemb = (const float*)d_in[2];
    const float* ewih = (const float*)d_in[3];
    const float* ewhh = (const float*)d_in[4];
    const float* ebih = (const float*)d_in[5];
    const float* ebhh = (const float*)d_in[6];
    const float* wq   = (const float*)d_in[7];
    const float* bq   = (const float*)d_in[8];
    const float* wk   = (const float*)d_in[9];
    const float* bk   = (const float*)d_in[10];
    const float* wsv  = (const float*)d_in[11];
    const float* bsv  = (const float*)d_in[12];
    const float* demb = (const float*)d_in[13];
    const float* dwih = (const float*)d_in[14];
    const float* dwhh = (const float*)d_in[15];
    const float* dbih = (const float*)d_in[16];
    const float* dbhh = (const float*)d_in[17];
    const float* wo   = (const float*)d_in[18];
    const float* bo   = (const float*)d_in[19];
    float* out = (float*)d_out;

    float* w = (float*)d_ws;
    float* enc_gi  = w;                                // [B*S][3H]
    float* dec_gi  = enc_gi  + (size_t)BB * SS * GG;   // [TD*B][3H]
    float* enc_out = dec_gi  + (size_t)TD * BB * GG;   // [B*S][H]
    float* keys    = enc_out + (size_t)BB * SS * HH;   // [B*S][H]
    float* h2all   = keys    + (size_t)BB * SS * HH;   // [TD*B][H]
    float* hA      = h2all   + (size_t)TD * BB * HH;   // hT4 [k/4][b][4]
    float* hB      = hA + BB * HH;
    float* qrow    = hB + BB * HH;                     // [B][H]
    float* ctxT4   = qrow + BB * HH;                   // hT4 layout
    int*   didx    = (int*)(ctxT4 + BB * HH);          // [TD*B]
    int*   barE    = didx + TD * BB + 64;
    int*   barD    = barE + 64;

    float* attn_out = out + (size_t)BB * TD * VV;

    hipMemsetAsync(barE, 0, 512, stream);
    k_dec_idx<<<dim3((TD * BB + 255) / 256), 256, 0, stream>>>(tgt, didx);

    // enc_gi = gather(enc_embed)@enc_w_ih^T + b_ih
    k_gemm<<<dim3(GG / 64, (BB * SS) / 64), 256, 0, stream>>>(
        eemb, ewih, ebih, enc_gi, src, BB * SS, GG, EE, EE, EE, GG, 0);
    // dec_gi = gather(dec_embed)@dec_w_ih[:, :E]^T + b_ih
    k_gemm<<<dim3(GG / 64, (TD * BB + 63) / 64), 256, 0, stream>>>(
        demb, dwih, dbih, dec_gi, didx, TD * BB, GG, EE, EE, EE + HH, GG, 0);

    p_enc<<<dim3(NBE), dim3(NTHR), 0, stream>>>(
        enc_gi, ewhh, ebhh, hA, hB, enc_out, barE);

    // keys = enc_out @ wk^T + bk
    k_gemm<<<dim3(HH / 64, (BB * SS) / 64), 256, 0, stream>>>(
        enc_out, wk, bk, keys, nullptr, BB * SS, HH, HH, HH, HH, HH, 0);

    p_dec<<<dim3(NBD), dim3(NTHR), 0, stream>>>(
        dec_gi, dwhh, dbhh, dwih, wq, bq, keys, wsv, bsv, src, enc_out,
        hA, hB, qrow, ctxT4, h2all, attn_out, barD);

    // logits = h2all @ wo^T + bo, rows permuted (t*B+b) -> (b*TD+t)
    k_gemm<<<dim3(VV / 64, (TD * BB + 63) / 64), 256, 0, stream>>>(
        h2all, wo, bo, out, nullptr, TD * BB, VV, HH, HH, HH, VV, 1);
}